// Round 4
// baseline (391.551 us; speedup 1.0000x reference)
//
#include <hip/hip_runtime.h>
#include <math.h>

constexpr int BATCH = 65536;
constexpr int DIM = 1024;
constexpr int NPASS = 5;  // pass 0 real; passes 1..4 laundered (calibration probe)

// tanh^2(y) via fast exp: tanh(y) = 1 - 2/(exp(2y)+1). Stable for all y.
__device__ __forceinline__ float tanh_sq(float y) {
    float t = __expf(2.0f * y);                 // v_exp_f32 path
    float r = __builtin_amdgcn_rcpf(t + 1.0f);  // fast rcp
    float h = 1.0f - 2.0f * r;
    return h * h;
}

// One wave per row; lane l covers cols {c*256 + l*4 .. +3}, c=0..3 -> float4,
// wave reads contiguous 1 KiB per chunk. w/b in registers.
// CALIBRATION: NPASS passes over each row; only pass 0 contributes to out.
// Extra passes use an asm-laundered offset (no CSE) and asm keep-alive (no DCE)
// so they generate real HBM traffic with the identical access pattern.
__global__ __launch_bounds__(256) void simplenet_probe(
        const float* __restrict__ x, const float* __restrict__ w,
        const float* __restrict__ b, float* __restrict__ out, int num_waves) {
    const int lane = threadIdx.x & 63;
    const int gwave = (blockIdx.x * blockDim.x + threadIdx.x) >> 6;

    float4 wv[4], bv[4];
#pragma unroll
    for (int c = 0; c < 4; ++c) {
        const int col = c * 256 + lane * 4;
        wv[c] = *reinterpret_cast<const float4*>(w + col);
        bv[c] = *reinterpret_cast<const float4*>(b + col);
    }

    for (int row = gwave; row < BATCH; row += num_waves) {
        float acc = 0.0f;
#pragma unroll
        for (int p = 0; p < NPASS; ++p) {
            // Element offset of this lane's first float4 in row. Launder so the
            // compiler cannot prove pass p reads the same addresses as pass 0.
            unsigned off = (unsigned)row * DIM + (unsigned)lane * 4;
            asm volatile("" : "+v"(off));
            const float* __restrict__ xr = x + off;
            float pacc = 0.0f;
#pragma unroll
            for (int c = 0; c < 4; ++c) {
                const float4 xv = *reinterpret_cast<const float4*>(xr + c * 256);
                pacc += tanh_sq(fmaf(xv.x, wv[c].x, bv[c].x));
                pacc += tanh_sq(fmaf(xv.y, wv[c].y, bv[c].y));
                pacc += tanh_sq(fmaf(xv.z, wv[c].z, bv[c].z));
                pacc += tanh_sq(fmaf(xv.w, wv[c].w, bv[c].w));
            }
            if (p == 0) acc = pacc;
            else asm volatile("" :: "v"(pacc));  // keep pass alive, discard value
        }
        // 64-lane butterfly reduce
#pragma unroll
        for (int s = 32; s; s >>= 1) acc += __shfl_xor(acc, s);
        if (lane == 0) out[row] = acc;
    }
}

extern "C" void kernel_launch(void* const* d_in, const int* in_sizes, int n_in,
                              void* d_out, int out_size, void* d_ws, size_t ws_size,
                              hipStream_t stream) {
    const float* x = (const float*)d_in[0];
    const float* w = (const float*)d_in[1];
    const float* b = (const float*)d_in[2];
    float* out = (float*)d_out;

    constexpr int threads = 256;
    constexpr int blocks = 2048;                    // 8192 waves, 8 rows/wave
    constexpr int num_waves = blocks * (threads / 64);
    simplenet_probe<<<blocks, threads, 0, stream>>>(x, w, b, out, num_waves);
}